// Round 1
// baseline (74.248 us; speedup 1.0000x reference)
//
#include <hip/hip_runtime.h>
#include <hip/hip_bf16.h>

#define NROWS 8192
#define MCOLS 8192
#define DK    64

typedef __attribute__((ext_vector_type(8))) short bf16x8;
typedef __attribute__((ext_vector_type(4))) float f32x4;

__device__ __forceinline__ float softplus_f(float x) {
    // matches jnp.where(x > 36, x, log1p(exp(min(x, 36))))
    return x > 36.0f ? x : log1pf(expf(fminf(x, 36.0f)));
}

__device__ __forceinline__ unsigned short to_bf16(float x) {
    unsigned int u = __float_as_uint(x);
    u += 0x7fffu + ((u >> 16) & 1u);   // round-to-nearest-even
    return (unsigned short)(u >> 16);
}
__device__ __forceinline__ float from_bf16(unsigned short h) {
    return __uint_as_float(((unsigned int)h) << 16);
}

// 128x128 tile per 256-thread workgroup; 4 waves in 2x2, each wave does 64x64.
// cross = Xs . Zs^T via bf16 hi/lo split: Ah*Bh + Ah*Bl + Al*Bh (fp32 accum).
__launch_bounds__(256, 2)
__global__ void rbf_kernel(const float* __restrict__ X, const float* __restrict__ Z,
                           const float* __restrict__ lraw, const float* __restrict__ sraw,
                           float* __restrict__ out) {
    // LDS: Ah[0,16K) Al[16K,32K) Bh[32K,48K) Bl[48K,64K), each [128 rows][128 B]
    __shared__ __align__(16) char smem[65536];
    __shared__ float part[256][8];   // per-(row,kchunk) partial |v|^2
    __shared__ float hxz[256];       // 0.5*|Xs_r|^2 (0..127), 0.5*|Zs_c|^2 (128..255)
    __shared__ float wsc[DK];
    __shared__ float sigf_s;

    const int tid = threadIdx.x;
    const int tR = blockIdx.y;
    const int tC = blockIdx.x;

    if (tid < DK) wsc[tid] = 1.0f / softplus_f(lraw[tid]);  // w = 1/l
    if (tid == 255) sigf_s = softplus_f(sraw[0]);
    __syncthreads();

    // ---- stage X/Z tiles: scale by w, split to bf16 hi/lo, accumulate norms ----
    #pragma unroll
    for (int i = 0; i < 8; ++i) {
        int s = tid + i * 256;       // 0..2047 slots of 8 elements
        int rfull = s >> 3;          // 0..255 (A rows then B rows)
        int r = rfull & 127;
        int kc = s & 7;
        bool isB = rfull >= 128;
        const float* src = isB ? (Z + (size_t)(tC * 128 + r) * DK + kc * 8)
                               : (X + (size_t)(tR * 128 + r) * DK + kc * 8);
        float4 v0 = *(const float4*)(src);
        float4 v1 = *(const float4*)(src + 4);
        float f[8] = {v0.x, v0.y, v0.z, v0.w, v1.x, v1.y, v1.z, v1.w};
        bf16x8 hv, lv;
        float sq = 0.0f;
        #pragma unroll
        for (int j = 0; j < 8; ++j) {
            float fv = f[j] * wsc[kc * 8 + j];
            sq += fv * fv;
            unsigned short h = to_bf16(fv);
            hv[j] = (short)h;
            lv[j] = (short)to_bf16(fv - from_bf16(h));
        }
        part[rfull][kc] = sq;
        int halfOff = isB ? 32768 : 0;
        int byteOff = r * 128 + ((kc * 16) ^ ((r & 7) << 4));  // XOR swizzle
        *(bf16x8*)(smem + halfOff + byteOff) = hv;
        *(bf16x8*)(smem + halfOff + 16384 + byteOff) = lv;
    }
    __syncthreads();

    {   // reduce 8 k-chunk partials -> 0.5*|row|^2
        float s0 = 0.0f;
        #pragma unroll
        for (int j = 0; j < 8; ++j) s0 += part[tid][j];
        hxz[tid] = 0.5f * s0;
    }
    __syncthreads();

    // ---- MFMA: each wave computes a 64x64 block as 4x4 fragments of 16x16 ----
    const int lane = tid & 63;
    const int wid  = tid >> 6;
    const int wr = wid >> 1, wc = wid & 1;
    const int lr = lane & 15;    // A-row / B-col within fragment
    const int lg = lane >> 4;    // k-group (0..3)
    const int swz = (lr & 7) << 4;

    f32x4 acc[4][4];
    #pragma unroll
    for (int a = 0; a < 4; ++a)
        #pragma unroll
        for (int b = 0; b < 4; ++b) acc[a][b] = f32x4{0.f, 0.f, 0.f, 0.f};

    #pragma unroll
    for (int pass = 0; pass < 3; ++pass) {
        const char* Ap = smem + ((pass == 2) ? 16384 : 0);          // Al on pass 2
        const char* Bp = smem + 32768 + ((pass == 1) ? 16384 : 0);  // Bl on pass 1
        #pragma unroll
        for (int ks = 0; ks < 2; ++ks) {
            int kb = ((lg * 16 + ks * 64) ^ swz);
            bf16x8 af[4], bfr[4];
            #pragma unroll
            for (int mi = 0; mi < 4; ++mi) {
                int row = wr * 64 + mi * 16 + lr;
                af[mi] = *(const bf16x8*)(Ap + row * 128 + kb);
            }
            #pragma unroll
            for (int ni = 0; ni < 4; ++ni) {
                int col = wc * 64 + ni * 16 + lr;
                bfr[ni] = *(const bf16x8*)(Bp + col * 128 + kb);
            }
            #pragma unroll
            for (int mi = 0; mi < 4; ++mi)
                #pragma unroll
                for (int ni = 0; ni < 4; ++ni)
                    acc[mi][ni] = __builtin_amdgcn_mfma_f32_16x16x32_bf16(
                        af[mi], bfr[ni], acc[mi][ni], 0, 0, 0);
        }
    }

    // ---- epilogue: val = sigf * exp(cross - 0.5|x|^2 - 0.5|z|^2), stream out ----
    const float sf = sigf_s;
    #pragma unroll
    for (int mi = 0; mi < 4; ++mi) {
        int row0 = wr * 64 + mi * 16 + lg * 4;   // C/D: col=lane&15, row=lg*4+reg
        #pragma unroll
        for (int ni = 0; ni < 4; ++ni) {
            int col = wc * 64 + ni * 16 + lr;
            float hz = hxz[128 + col];
            size_t obase = (size_t)(tR * 128 + row0) * MCOLS + (size_t)(tC * 128 + col);
            #pragma unroll
            for (int j = 0; j < 4; ++j) {
                float arg = acc[mi][ni][j] - (hxz[row0 + j] + hz);
                __builtin_nontemporal_store(sf * __expf(arg), out + obase + (size_t)j * MCOLS);
            }
        }
    }
}

extern "C" void kernel_launch(void* const* d_in, const int* in_sizes, int n_in,
                              void* d_out, int out_size, void* d_ws, size_t ws_size,
                              hipStream_t stream) {
    const float* X = (const float*)d_in[0];
    const float* Z = (const float*)d_in[1];
    const float* l = (const float*)d_in[2];
    const float* s = (const float*)d_in[3];
    float* out = (float*)d_out;
    dim3 grid(MCOLS / 128, NROWS / 128);
    rbf_kernel<<<grid, dim3(256), 0, stream>>>(X, Z, l, s, out);
}

// Round 2
// 67.820 us; speedup vs baseline: 1.0948x; 1.0948x over previous
//
#include <hip/hip_runtime.h>
#include <hip/hip_bf16.h>

#define NROWS 8192
#define MCOLS 8192
#define DK    64

typedef __attribute__((ext_vector_type(8))) short bf16x8;
typedef __attribute__((ext_vector_type(4))) float f32x4;

__device__ __forceinline__ float softplus_f(float x) {
    // matches jnp.where(x > 36, x, log1p(exp(min(x, 36))))
    return x > 36.0f ? x : log1pf(expf(fminf(x, 36.0f)));
}

__device__ __forceinline__ unsigned short to_bf16(float x) {
    unsigned int u = __float_as_uint(x);
    u += 0x7fffu + ((u >> 16) & 1u);   // round-to-nearest-even
    return (unsigned short)(u >> 16);
}
__device__ __forceinline__ float from_bf16(unsigned short h) {
    return __uint_as_float(((unsigned int)h) << 16);
}

// 128x128 tile per 512-thread workgroup; 8 waves in 4x2, each wave does 32x64.
// cross = Xs . Zs^T via bf16 hi/lo split: Ah*Bh + Ah*Bl + Al*Bh (fp32 accum).
// LDS 65.3 KB -> 2 blocks/CU -> 16 waves/CU (4/SIMD), double the latency hiding
// of the 256-thread version (which was 2 waves/SIMD).
__launch_bounds__(512, 4)
__global__ void rbf_kernel(const float* __restrict__ X, const float* __restrict__ Z,
                           const float* __restrict__ lraw, const float* __restrict__ sraw,
                           float* __restrict__ out) {
    // LDS: Ah[0,16K) Al[16K,32K) Bh[32K,48K) Bl[48K,64K), each [128 rows][128 B]
    __shared__ __align__(16) char smem[65536];
    __shared__ float hxz[256];       // 0.5*|Xs_r|^2 (0..127), 0.5*|Zs_c|^2 (128..255)
    __shared__ float wsc[DK];
    __shared__ float sigf_s;

    const int tid = threadIdx.x;
    const int tR = blockIdx.y;
    const int tC = blockIdx.x;

    if (tid < DK) wsc[tid] = 1.0f / softplus_f(lraw[tid]);  // w = 1/l
    if (tid == 511) sigf_s = softplus_f(sraw[0]);
    __syncthreads();

    // ---- stage X/Z tiles: scale by w, split to bf16 hi/lo; shfl-reduce norms ----
    // 256 rows x 8 k-chunks of 8 elems; the 8 chunks of a row sit in 8
    // consecutive lanes of one wave -> 3x shfl_xor gives the row norm.
    #pragma unroll
    for (int i = 0; i < 4; ++i) {
        int rfull = i * 64 + (tid >> 3);  // 0..255 (A rows then B rows)
        int r = rfull & 127;
        int kc = tid & 7;
        bool isB = rfull >= 128;
        const float* src = isB ? (Z + (size_t)(tC * 128 + r) * DK + kc * 8)
                               : (X + (size_t)(tR * 128 + r) * DK + kc * 8);
        float4 v0 = *(const float4*)(src);
        float4 v1 = *(const float4*)(src + 4);
        float f[8] = {v0.x, v0.y, v0.z, v0.w, v1.x, v1.y, v1.z, v1.w};
        bf16x8 hv, lv;
        float sq = 0.0f;
        #pragma unroll
        for (int j = 0; j < 8; ++j) {
            float fv = f[j] * wsc[kc * 8 + j];
            sq += fv * fv;
            unsigned short h = to_bf16(fv);
            hv[j] = (short)h;
            lv[j] = (short)to_bf16(fv - from_bf16(h));
        }
        sq += __shfl_xor(sq, 1);
        sq += __shfl_xor(sq, 2);
        sq += __shfl_xor(sq, 4);
        if (kc == 0) hxz[rfull] = 0.5f * sq;
        int halfOff = isB ? 32768 : 0;
        int byteOff = r * 128 + ((kc * 16) ^ ((r & 7) << 4));  // XOR swizzle
        *(bf16x8*)(smem + halfOff + byteOff) = hv;
        *(bf16x8*)(smem + halfOff + 16384 + byteOff) = lv;
    }
    __syncthreads();

    // ---- MFMA: each wave computes a 32x64 block as 2x4 fragments of 16x16 ----
    const int lane = tid & 63;
    const int wid  = tid >> 6;       // 0..7
    const int wr = wid >> 1;         // 0..3 (row block of 32)
    const int wc = wid & 1;          // 0..1 (col block of 64)
    const int lr = lane & 15;        // A-row / B-col within fragment
    const int lg = lane >> 4;        // k-group (0..3)
    const int swz = (lr & 7) << 4;

    f32x4 acc[2][4];
    #pragma unroll
    for (int a = 0; a < 2; ++a)
        #pragma unroll
        for (int b = 0; b < 4; ++b) acc[a][b] = f32x4{0.f, 0.f, 0.f, 0.f};

    #pragma unroll
    for (int pass = 0; pass < 3; ++pass) {
        const char* Ap = smem + ((pass == 2) ? 16384 : 0);          // Al on pass 2
        const char* Bp = smem + 32768 + ((pass == 1) ? 16384 : 0);  // Bl on pass 1
        #pragma unroll
        for (int ks = 0; ks < 2; ++ks) {
            int kb = ((lg * 16 + ks * 64) ^ swz);
            bf16x8 af[2], bfr[4];
            #pragma unroll
            for (int mi = 0; mi < 2; ++mi) {
                int row = wr * 32 + mi * 16 + lr;
                af[mi] = *(const bf16x8*)(Ap + row * 128 + kb);
            }
            #pragma unroll
            for (int ni = 0; ni < 4; ++ni) {
                int col = wc * 64 + ni * 16 + lr;
                bfr[ni] = *(const bf16x8*)(Bp + col * 128 + kb);
            }
            #pragma unroll
            for (int mi = 0; mi < 2; ++mi)
                #pragma unroll
                for (int ni = 0; ni < 4; ++ni)
                    acc[mi][ni] = __builtin_amdgcn_mfma_f32_16x16x32_bf16(
                        af[mi], bfr[ni], acc[mi][ni], 0, 0, 0);
        }
    }

    // ---- epilogue: val = sigf * exp(cross - 0.5|x|^2 - 0.5|z|^2) ----
    const float sf = sigf_s;
    #pragma unroll
    for (int mi = 0; mi < 2; ++mi) {
        int row0 = wr * 32 + mi * 16 + lg * 4;   // C/D: col=lane&15, row=lg*4+reg
        #pragma unroll
        for (int ni = 0; ni < 4; ++ni) {
            int col = wc * 64 + ni * 16 + lr;
            float hz = hxz[128 + col];
            size_t obase = (size_t)(tR * 128 + row0) * MCOLS + (size_t)(tC * 128 + col);
            #pragma unroll
            for (int j = 0; j < 4; ++j) {
                float arg = acc[mi][ni][j] - (hxz[row0 + j] + hz);
                out[obase + (size_t)j * MCOLS] = sf * __expf(arg);
            }
        }
    }
}

extern "C" void kernel_launch(void* const* d_in, const int* in_sizes, int n_in,
                              void* d_out, int out_size, void* d_ws, size_t ws_size,
                              hipStream_t stream) {
    const float* X = (const float*)d_in[0];
    const float* Z = (const float*)d_in[1];
    const float* l = (const float*)d_in[2];
    const float* s = (const float*)d_in[3];
    float* out = (float*)d_out;
    dim3 grid(MCOLS / 128, NROWS / 128);
    rbf_kernel<<<grid, dim3(512), 0, stream>>>(X, Z, l, s, out);
}